// Round 3
// baseline (673.018 us; speedup 1.0000x reference)
//
#include <hip/hip_runtime.h>
#include <hip/hip_bf16.h>

#define DEVI __device__ __forceinline__

typedef __attribute__((ext_vector_type(8))) short  short8;
typedef __attribute__((ext_vector_type(4))) float  floatx4;
typedef __attribute__((ext_vector_type(8))) __bf16 bf16x8;

DEVI float b2f(unsigned short u){ union{unsigned int i; float f;} x; x.i=((unsigned int)u)<<16; return x.f; }
DEVI unsigned short f2b(float f){
  union{float ff; unsigned int i;} x; x.ff=f;
  unsigned int r = x.i + 0x7fffu + ((x.i>>16)&1u);
  return (unsigned short)(r>>16);
}

DEVI void lds_dma16(const void* g, void* l){
  __builtin_amdgcn_global_load_lds((const __attribute__((address_space(1))) void*)g,
                                   (__attribute__((address_space(3))) void*)l, 16, 0, 0);
}

DEVI floatx4 mfma_bf16(short8 a, short8 b, floatx4 c){
  return __builtin_amdgcn_mfma_f32_16x16x32_bf16(
      __builtin_bit_cast(bf16x8, a), __builtin_bit_cast(bf16x8, b), c, 0, 0, 0);
}

// LDS swizzle (both-sides XOR, rule 21): tile [128][64] bf16, 8-el chunks.
// LDS(row, c) holds global chunk c ^ (row&7). DMA dest stays linear
// (base + lane*16 == t*16B, verified lane-linear); the SOURCE column is
// inverse-permuted. Reg-staged writes XOR the ds_write address. Fragment
// reads XOR with (l15&7)*8.

// ---------------------------------------------------------------------------
// f32 -> bf16 (single) elementwise
// ---------------------------------------------------------------------------
__global__ void cvt_kernel(const float* __restrict__ src, unsigned short* __restrict__ dst, int n8)
{
  const int i = blockIdx.x * 256 + threadIdx.x;
  if (i >= n8) return;
  floatx4 a = ((const floatx4*)src)[2*(size_t)i];
  floatx4 b = ((const floatx4*)src)[2*(size_t)i + 1];
  short8 o;
  o[0]=(short)f2b(a[0]); o[1]=(short)f2b(a[1]); o[2]=(short)f2b(a[2]); o[3]=(short)f2b(a[3]);
  o[4]=(short)f2b(b[0]); o[5]=(short)f2b(b[1]); o[6]=(short)f2b(b[2]); o[7]=(short)f2b(b[3]);
  *(short8*)&dst[(size_t)i*8] = o;
}

// ---------------------------------------------------------------------------
// f32 -> (hi, lo) bf16 split: hi = rne(x), lo = rne(x - hi).
// ---------------------------------------------------------------------------
__global__ void cvt_split(const float* __restrict__ src, unsigned short* __restrict__ dh,
                          unsigned short* __restrict__ dl, int n8)
{
  const int i = blockIdx.x * 256 + threadIdx.x;
  if (i >= n8) return;
  floatx4 a = ((const floatx4*)src)[2*(size_t)i];
  floatx4 b = ((const floatx4*)src)[2*(size_t)i + 1];
  short8 h, l;
  #pragma unroll
  for (int j = 0; j < 8; j++){
    float x = (j < 4) ? a[j] : b[j-4];
    unsigned short hb = f2b(x);
    h[j] = (short)hb;
    l[j] = (short)f2b(x - b2f(hb));
  }
  *(short8*)&dh[(size_t)i*8] = h;
  *(short8*)&dl[(size_t)i*8] = l;
}

// ---------------------------------------------------------------------------
// C(bf16) = A(f32) @ Bw(bf16)^T.  BK=64, swizzled LDS, T14 A-prefetch.
// GATE=1: epilogue applies z from zs/zc and silu before the bf16 store.
// ---------------------------------------------------------------------------
template<int GATE>
__global__ __launch_bounds__(256, 2)
void gemm_af32(const float* __restrict__ A, const unsigned short* __restrict__ Bw,
               unsigned short* __restrict__ C, int M, int N, int K,
               const float* __restrict__ zs, const float* __restrict__ zc)
{
  __shared__ __align__(16) short As[128*64];
  __shared__ __align__(16) short Bs[128*64];
  const int t    = threadIdx.x;
  const int lane = t & 63;
  const int w    = t >> 6, wm = w >> 1, wn = w & 1;
  const int l15  = lane & 15, kg = lane >> 4;
  const int sx   = (l15 & 7) * 8;                    // read-side swizzle
  const long bm  = (long)blockIdx.y * 128, bn = (long)blockIdx.x * 128;

  const int sr = t >> 3, sc8 = (t & 7) * 8;
  const int scx = sc8 ^ ((sr & 7) * 8);              // write/source-side swizzle
  const unsigned short* pb[4];
  const float* pa[4];
  short *lb[4], *la[4];
  #pragma unroll
  for (int u = 0; u < 4; u++){
    pb[u] = Bw + (bn + sr + u*32) * (size_t)K + scx; // inverse-swizzled source
    pa[u] = A  + (bm + sr + u*32) * (size_t)K + sc8; // plain source
    lb[u] = &Bs[(sr + u*32)*64 + sc8];               // linear DMA dest
    la[u] = &As[(sr + u*32)*64 + scx];               // swizzled ds_write dest
  }

  floatx4 acc[4][4] = {};
  floatx4 cur[8], nxt[8];
  #pragma unroll
  for (int u = 0; u < 4; u++){
    cur[2*u]   = *(const floatx4*)(pa[u]);
    cur[2*u+1] = *(const floatx4*)(pa[u] + 4);
  }

  for (int k0 = 0; k0 < K; k0 += 64){
    __syncthreads();
    #pragma unroll
    for (int u = 0; u < 4; u++) lds_dma16(pb[u] + k0, lb[u]);
    #pragma unroll
    for (int u = 0; u < 4; u++){
      short8 h;
      #pragma unroll
      for (int j = 0; j < 8; j++){
        float x = (j < 4) ? cur[2*u][j] : cur[2*u+1][j-4];
        h[j] = (short)f2b(x);
      }
      *(short8*)la[u] = h;
    }
    __syncthreads();
    // T14: issue next A-tile loads here; they hide under the MFMAs and
    // drain at the next barrier's vmcnt(0).
    const int kn = (k0 + 64 < K) ? (k0 + 64) : k0;
    #pragma unroll
    for (int u = 0; u < 4; u++){
      nxt[2*u]   = *(const floatx4*)(pa[u] + kn);
      nxt[2*u+1] = *(const floatx4*)(pa[u] + kn + 4);
    }
    #pragma unroll
    for (int ks = 0; ks < 2; ks++){
      short8 af[4], bv[4];
      #pragma unroll
      for (int i = 0; i < 4; i++){
        af[i] = *(const short8*)&As[(wm*64 + i*16 + l15)*64 + ((ks*32 + kg*8) ^ sx)];
        bv[i] = *(const short8*)&Bs[(wn*64 + i*16 + l15)*64 + ((ks*32 + kg*8) ^ sx)];
      }
      #pragma unroll
      for (int i = 0; i < 4; i++)
        #pragma unroll
        for (int j = 0; j < 4; j++)
          acc[i][j] = mfma_bf16(af[i], bv[j], acc[i][j]);
    }
    #pragma unroll
    for (int r8 = 0; r8 < 8; r8++) cur[r8] = nxt[r8];
  }

  if (GATE){
    #pragma unroll
    for (int i = 0; i < 4; i++){
      const long mb = bm + wm*64 + i*16 + kg*4;
      #pragma unroll
      for (int r = 0; r < 4; r++){
        const long row = mb + r;
        const int  ss  = (int)(row & 4095);
        const long bb  = row >> 12;
        const float* zr = (ss < 64) ? (zs + (((size_t)(bb*64 + ss)) << 10))
                                    : (zc + ((size_t)bb << 10));
        #pragma unroll
        for (int j = 0; j < 4; j++){
          const long n = bn + wn*64 + j*16 + l15;
          float g = acc[i][j][r] * zr[n];
          float sig = 1.0f / (1.0f + __expf(-g));
          C[(size_t)row * N + n] = f2b(g * sig);
        }
      }
    }
  } else {
    #pragma unroll
    for (int i = 0; i < 4; i++){
      const long mb = bm + wm*64 + i*16 + kg*4;
      #pragma unroll
      for (int j = 0; j < 4; j++){
        const long n = bn + wn*64 + j*16 + l15;
        #pragma unroll
        for (int r = 0; r < 4; r++)
          C[(size_t)(mb + r) * N + n] = f2b(acc[i][j][r]);
      }
    }
  }
}

// ---------------------------------------------------------------------------
// C(f32) = xpos( A(f32) @ B^T ) with split-bf16 (3-term). BK=64, swizzled LDS,
// T14 A-prefetch (cur/nxt). xpos fused in epilogue: partner col is lane^1.
// QG=1: A-row gather r -> (r>>6)*4096 + (r&63), position = row & 63.
// ---------------------------------------------------------------------------
template<int QG>
__global__ __launch_bounds__(256, 2)
void gemm_split(const float* __restrict__ A, const unsigned short* __restrict__ Bh,
                const unsigned short* __restrict__ Bl, float* __restrict__ C,
                int M, int N, int K)
{
  __shared__ __align__(16) short Ash[128*64];
  __shared__ __align__(16) short Asl[128*64];
  __shared__ __align__(16) short Bsh[128*64];
  __shared__ __align__(16) short Bsl[128*64];
  const int t    = threadIdx.x;
  const int lane = t & 63;
  const int w    = t >> 6, wm = w >> 1, wn = w & 1;
  const int l15  = lane & 15, kg = lane >> 4;
  const int sx   = (l15 & 7) * 8;
  const long bm  = (long)blockIdx.y * 128, bn = (long)blockIdx.x * 128;

  const int sr = t >> 3, sc8 = (t & 7) * 8;
  const int scx = sc8 ^ ((sr & 7) * 8);
  const unsigned short *pbh[4], *pbl[4];
  const float* pa[4];
  short *lbh[4], *lbl[4], *lah[4], *lal[4];
  #pragma unroll
  for (int u = 0; u < 4; u++){
    pbh[u] = Bh + (bn + sr + u*32) * (size_t)K + scx;
    pbl[u] = Bl + (bn + sr + u*32) * (size_t)K + scx;
    long ar = bm + sr + u*32;
    if (QG) ar = (ar >> 6) * 4096 + (ar & 63);
    pa[u]  = A + ar * (size_t)K + sc8;
    lbh[u] = &Bsh[(sr + u*32)*64 + sc8];
    lbl[u] = &Bsl[(sr + u*32)*64 + sc8];
    lah[u] = &Ash[(sr + u*32)*64 + scx];
    lal[u] = &Asl[(sr + u*32)*64 + scx];
  }

  floatx4 acc[4][4] = {};
  floatx4 cur[8], nxt[8];
  #pragma unroll
  for (int u = 0; u < 4; u++){
    cur[2*u]   = *(const floatx4*)(pa[u]);
    cur[2*u+1] = *(const floatx4*)(pa[u] + 4);
  }

  for (int k0 = 0; k0 < K; k0 += 64){
    __syncthreads();
    #pragma unroll
    for (int u = 0; u < 4; u++){
      lds_dma16(pbh[u] + k0, lbh[u]);
      lds_dma16(pbl[u] + k0, lbl[u]);
    }
    #pragma unroll
    for (int u = 0; u < 4; u++){
      short8 h, l;
      #pragma unroll
      for (int j = 0; j < 8; j++){
        float x = (j < 4) ? cur[2*u][j] : cur[2*u+1][j-4];
        unsigned short hb = f2b(x);
        h[j] = (short)hb;
        l[j] = (short)f2b(x - b2f(hb));
      }
      *(short8*)lah[u] = h;
      *(short8*)lal[u] = l;
    }
    __syncthreads();
    // T14: next A-tile loads overlap the 96 MFMAs below.
    const int kn = (k0 + 64 < K) ? (k0 + 64) : k0;
    #pragma unroll
    for (int u = 0; u < 4; u++){
      nxt[2*u]   = *(const floatx4*)(pa[u] + kn);
      nxt[2*u+1] = *(const floatx4*)(pa[u] + kn + 4);
    }
    #pragma unroll
    for (int ks = 0; ks < 2; ks++){
      short8 afh[4], afl[4], bvh[4], bvl[4];
      #pragma unroll
      for (int i = 0; i < 4; i++){
        const int ro = (ks*32 + kg*8) ^ sx;
        afh[i] = *(const short8*)&Ash[(wm*64 + i*16 + l15)*64 + ro];
        afl[i] = *(const short8*)&Asl[(wm*64 + i*16 + l15)*64 + ro];
        bvh[i] = *(const short8*)&Bsh[(wn*64 + i*16 + l15)*64 + ro];
        bvl[i] = *(const short8*)&Bsl[(wn*64 + i*16 + l15)*64 + ro];
      }
      #pragma unroll
      for (int i = 0; i < 4; i++)
        #pragma unroll
        for (int j = 0; j < 4; j++){
          acc[i][j] = mfma_bf16(afh[i], bvh[j], acc[i][j]);
          acc[i][j] = mfma_bf16(afh[i], bvl[j], acc[i][j]);
          acc[i][j] = mfma_bf16(afl[i], bvh[j], acc[i][j]);
        }
    }
    #pragma unroll
    for (int r8 = 0; r8 < 8; r8++) cur[r8] = nxt[r8];
  }

  // fused xpos epilogue. col pairs (2ip, 2ip+1) sit in lanes (l, l^1).
  const int smask = QG ? 63 : 4095;
  #pragma unroll
  for (int j = 0; j < 4; j++){
    const long n  = bn + wn*64 + j*16 + l15;
    const int  ip = (int)(n >> 1);
    const float lsv  = __logf((2.0f*ip + 409.6f) * (1.0f/1433.6f));
    const float invf = __expf(-(float)ip * (9.2103403720f/512.0f));  // 10000^(-ip/512)
    const float sgn  = (n & 1) ? 1.0f : -1.0f;
    #pragma unroll
    for (int i = 0; i < 4; i++){
      const long mb = bm + wm*64 + i*16 + kg*4;
      #pragma unroll
      for (int r = 0; r < 4; r++){
        float x = acc[i][j][r];
        float p = __shfl_xor(x, 1);
        const float fs = (float)((int)((mb + r) & smask));
        const float scale = __expf(lsv * fs * (1.0f/512.0f));
        float sn, cs;
        __sincosf(fs * invf, &sn, &cs);
        sn *= scale; cs *= scale;
        C[(size_t)(mb + r) * N + n] = x*cs + sgn*(p*sn);
      }
    }
  }
}

// ---------------------------------------------------------------------------
// Split-precision projection: P[b*2][e][d'] += sum_s wxw[e,s]*X[b][s,d'].
// ---------------------------------------------------------------------------
__global__ __launch_bounds__(256, 2)
void proj_split(const float* __restrict__ X0, const unsigned short* __restrict__ wxh,
                const unsigned short* __restrict__ wxl, float* __restrict__ P)
{
  __shared__ __align__(16) short Wsh[64*32];
  __shared__ __align__(16) short Wsl[64*32];
  __shared__ __align__(16) short Xth[64*40];
  __shared__ __align__(16) short Xtl[64*40];
  const int t = threadIdx.x, w = t >> 6, lane = t & 63;
  const int l15 = lane & 15, kg = lane >> 4;
  const int d0 = blockIdx.x * 64;
  const int b  = blockIdx.y;
  const float* X = X0 + (size_t)b * 4096 * 1024;
  const int s0 = blockIdx.z * 512;
  const int ssr = t >> 3, ddr = (t & 7) * 8;
  floatx4 acc[4] = {};

  for (int kk = 0; kk < 512; kk += 32){
    const int s = s0 + kk;
    floatx4 x0 = *(const floatx4*)&X[(size_t)(s + ssr) * 1024 + d0 + ddr];
    floatx4 x1 = *(const floatx4*)&X[(size_t)(s + ssr) * 1024 + d0 + ddr + 4];
    __syncthreads();
    lds_dma16(&wxh[(size_t)(t >> 2) * 4096 + s + (t & 3) * 8], &Wsh[t*8]);
    lds_dma16(&wxl[(size_t)(t >> 2) * 4096 + s + (t & 3) * 8], &Wsl[t*8]);
    float xv[8] = {x0[0],x0[1],x0[2],x0[3],x1[0],x1[1],x1[2],x1[3]};
    #pragma unroll
    for (int j = 0; j < 8; j++){
      unsigned short hb = f2b(xv[j]);
      Xth[(ddr + j) * 40 + ssr] = (short)hb;
      Xtl[(ddr + j) * 40 + ssr] = (short)f2b(xv[j] - b2f(hb));
    }
    __syncthreads();
    short8 afh = *(const short8*)&Wsh[(w*16 + l15)*32 + kg*8];
    short8 afl = *(const short8*)&Wsl[(w*16 + l15)*32 + kg*8];
    #pragma unroll
    for (int j = 0; j < 4; j++){
      short8 bvh = *(const short8*)&Xth[(j*16 + l15)*40 + kg*8];
      short8 bvl = *(const short8*)&Xtl[(j*16 + l15)*40 + kg*8];
      acc[j] = mfma_bf16(afh, bvh, acc[j]);
      acc[j] = mfma_bf16(afh, bvl, acc[j]);
      acc[j] = mfma_bf16(afl, bvh, acc[j]);
    }
  }
  float* Pb = P + (size_t)(b*2) * 65536;
  #pragma unroll
  for (int j = 0; j < 4; j++)
    #pragma unroll
    for (int r = 0; r < 4; r++)
      atomicAdd(&Pb[(w*16 + kg*4 + r) * 1024 + d0 + j*16 + l15], acc[j][r]);
}

// ---------------------------------------------------------------------------
// bf16 projection for V: P[b*2+1][e][d'] += sum_s wxw_h[e,s]*X[b][s,d']
// ---------------------------------------------------------------------------
__global__ __launch_bounds__(256, 2)
void proj_bf16(const unsigned short* __restrict__ X0, const unsigned short* __restrict__ wxw_bf,
               float* __restrict__ P)
{
  __shared__ __align__(16) short Ws[64*32];
  __shared__ __align__(16) short Xt[64*40];
  const int t = threadIdx.x, w = t >> 6, lane = t & 63;
  const int l15 = lane & 15, kg = lane >> 4;
  const int d0 = blockIdx.x * 64;
  const int b  = blockIdx.y;
  const unsigned short* X = X0 + (size_t)b * 4096 * 1024;
  const int s0 = blockIdx.z * 512;
  const int ssr = t >> 3, ddr = (t & 7) * 8;
  floatx4 acc[4] = {};

  for (int kk = 0; kk < 512; kk += 32){
    const int s = s0 + kk;
    short8 xv = *(const short8*)&X[(size_t)(s + ssr) * 1024 + d0 + ddr];
    __syncthreads();
    lds_dma16(&wxw_bf[(size_t)(t >> 2) * 4096 + s + (t & 3) * 8], &Ws[t*8]);
    #pragma unroll
    for (int j = 0; j < 8; j++) Xt[(ddr + j) * 40 + ssr] = xv[j];
    __syncthreads();
    short8 af = *(const short8*)&Ws[(w*16 + l15)*32 + kg*8];
    #pragma unroll
    for (int j = 0; j < 4; j++){
      short8 bv = *(const short8*)&Xt[(j*16 + l15)*40 + kg*8];
      acc[j] = mfma_bf16(af, bv, acc[j]);
    }
  }
  float* Pb = P + (size_t)(b*2 + 1) * 65536;
  #pragma unroll
  for (int j = 0; j < 4; j++)
    #pragma unroll
    for (int r = 0; r < 4; r++)
      atomicAdd(&Pb[(w*16 + kg*4 + r) * 1024 + d0 + j*16 + l15], acc[j][r]);
}

// ---------------------------------------------------------------------------
// Per (b,h) attention + group norm. 256 threads: wave w owns e-quarter for
// scores and g-quarter for outputs; scores round-trip through LDS.
// Masked score entries are literal ZEROS (matches reference softmax).
// ---------------------------------------------------------------------------
__global__ __launch_bounds__(256)
void attn_kernel(const float* __restrict__ P, const float* __restrict__ Qx,
                 const float* __restrict__ wxb,
                 const float* __restrict__ gnw, const float* __restrict__ gnb,
                 float* __restrict__ zs, float* __restrict__ zc)
{
  __shared__ __align__(16) float kps[64*64];   // [e][d]
  __shared__ __align__(16) float vps[64*64];   // [e][f]
  __shared__ __align__(16) float scs[64*65];   // [e][s], stride 65
  __shared__ float pm[256];
  __shared__ float ym[64];
  const int t = threadIdx.x;
  const int w = t >> 6, s = t & 63;
  const int b = blockIdx.x >> 4, h = blockIdx.x & 15;
  const float* Pk = P + (size_t)(2*b) * 65536 + h*64;
  const float* Pv = Pk + 65536;

  {
    const int e = t >> 2, c = (t & 3) * 16;
    const float wb = wxb[e];
    #pragma unroll
    for (int j = 0; j < 4; j++){
      floatx4 kv = *(const floatx4*)&Pk[(size_t)e*1024 + c + 4*j];
      floatx4 vv = *(const floatx4*)&Pv[(size_t)e*1024 + c + 4*j];
      kv.x += wb; kv.y += wb; kv.z += wb; kv.w += wb;
      vv.x += wb; vv.y += wb; vv.z += wb; vv.w += wb;
      *(floatx4*)&kps[e*64 + c + 4*j] = kv;
      *(floatx4*)&vps[e*64 + c + 4*j] = vv;
    }
  }
  __syncthreads();

  float qf[64];
  const floatx4* q4 = (const floatx4*)(Qx + (size_t)(b*64 + s)*1024 + h*64);
  #pragma unroll
  for (int i = 0; i < 16; i++){
    floatx4 qq = q4[i];
    qf[4*i] = qq.x; qf[4*i+1] = qq.y; qf[4*i+2] = qq.z; qf[4*i+3] = qq.w;
  }

  // scores for this wave's e-quarter -> LDS [e][s]
  #pragma unroll
  for (int eo = 0; eo < 16; eo++){
    const int e = w*16 + eo;
    const floatx4* kp4 = (const floatx4*)&kps[e*64];
    float dot = 0.f;
    #pragma unroll
    for (int d = 0; d < 16; d++){
      floatx4 kv = kp4[d];
      dot += qf[4*d]*kv.x + qf[4*d+1]*kv.y + qf[4*d+2]*kv.z + qf[4*d+3]*kv.w;
    }
    scs[e*65 + s] = dot;
  }
  // partial column-sum of vps for the zc tail
  {
    float am = 0.f;
    #pragma unroll
    for (int eo = 0; eo < 16; eo++) am += vps[(w*16 + eo)*64 + s];
    pm[t] = am;
  }
  __syncthreads();

  const float lg = -3.4657359028f - 0.1848392483f * (float)h;
  const float gamma = 1.0f - __expf(lg);
  float sc[64];
  #pragma unroll
  for (int e = 0; e < 64; e++) sc[e] = scs[e*65 + s];
  float dec = 1.0f;
  #pragma unroll
  for (int e = 0; e < 64; e++){
    bool on = (e >= s);
    sc[e] = on ? sc[e]*dec : 0.0f;
    if (on) dec *= gamma;
  }
  float mx = -1e30f;
  #pragma unroll
  for (int e = 0; e < 64; e++) mx = fmaxf(mx, sc[e]);
  float Z = 0.f;
  #pragma unroll
  for (int e = 0; e < 64; e++){ sc[e] = __expf(sc[e] - mx); Z += sc[e]; }
  const float rz = 1.0f / Z;

  #pragma unroll
  for (int go = 0; go < 4; go++){
    const int g = w*4 + go;
    floatx4 y = {0.f,0.f,0.f,0.f};
    #pragma unroll
    for (int e = 0; e < 64; e++){
      floatx4 vv = *(const floatx4*)&vps[e*64 + g*4];
      y += sc[e] * vv;
    }
    y *= rz;
    float mu = (y.x + y.y + y.z + y.w) * 0.25f;
    float a0 = y.x-mu, a1 = y.y-mu, a2 = y.z-mu, a3 = y.w-mu;
    float inv = rsqrtf((a0*a0 + a1*a1 + a2*a2 + a3*a3)*0.25f + 1e-5f);
    floatx4 o;
    o.x = a0*inv*gnw[g*4+0] + gnb[g*4+0];
    o.y = a1*inv*gnw[g*4+1] + gnb[g*4+1];
    o.z = a2*inv*gnw[g*4+2] + gnb[g*4+2];
    o.w = a3*inv*gnw[g*4+3] + gnb[g*4+3];
    *(floatx4*)&zs[(size_t)(b*64 + s)*1024 + h*64 + g*4] = o;
  }

  if (w == 0)
    ym[s] = (pm[s] + pm[64+s] + pm[128+s] + pm[192+s]) * (1.0f/64.0f);
  __syncthreads();
  if (t < 16){
    float a0 = ym[t*4], a1 = ym[t*4+1], a2 = ym[t*4+2], a3 = ym[t*4+3];
    float mu = (a0+a1+a2+a3)*0.25f;
    a0 -= mu; a1 -= mu; a2 -= mu; a3 -= mu;
    float inv = rsqrtf((a0*a0+a1*a1+a2*a2+a3*a3)*0.25f + 1e-5f);
    zc[(size_t)b*1024 + h*64 + t*4+0] = a0*inv*gnw[t*4+0] + gnb[t*4+0];
    zc[(size_t)b*1024 + h*64 + t*4+1] = a1*inv*gnw[t*4+1] + gnb[t*4+1];
    zc[(size_t)b*1024 + h*64 + t*4+2] = a2*inv*gnw[t*4+2] + gnb[t*4+2];
    zc[(size_t)b*1024 + h*64 + t*4+3] = a3*inv*gnw[t*4+3] + gnb[t*4+3];
  }
}

// ---------------------------------------------------------------------------
// C(f32) = A(bf16) @ B(bf16)^T — final GEMM, BK=64, swizzled LDS, both DMA.
// (256,3): ~140 VGPR body fits 170 cap -> 3 blocks/CU, 12 waves/CU.
// ---------------------------------------------------------------------------
__global__ __launch_bounds__(256, 3)
void gemm_bt(const unsigned short* __restrict__ A, const unsigned short* __restrict__ Bw,
             float* __restrict__ C, int M, int N, int K)
{
  __shared__ __align__(16) short As[128*64];
  __shared__ __align__(16) short Bs[128*64];
  const int t    = threadIdx.x;
  const int lane = t & 63;
  const int w    = t >> 6, wm = w >> 1, wn = w & 1;
  const int l15  = lane & 15, kg = lane >> 4;
  const int sx   = (l15 & 7) * 8;
  const long bm  = (long)blockIdx.y * 128, bn = (long)blockIdx.x * 128;

  const int sr = t >> 3, sc8 = (t & 7) * 8;
  const int scx = sc8 ^ ((sr & 7) * 8);
  const unsigned short *pa[4], *pb[4];
  short *la[4], *lb[4];
  #pragma unroll
  for (int u = 0; u < 4; u++){
    pa[u] = A  + (bm + sr + u*32) * (size_t)K + scx;
    pb[u] = Bw + (bn + sr + u*32) * (size_t)K + scx;
    la[u] = &As[(sr + u*32)*64 + sc8];
    lb[u] = &Bs[(sr + u*32)*64 + sc8];
  }

  floatx4 acc[4][4] = {};

  for (int k0 = 0; k0 < K; k0 += 64){
    __syncthreads();
    #pragma unroll
    for (int u = 0; u < 4; u++){
      lds_dma16(pa[u] + k0, la[u]);
      lds_dma16(pb[u] + k0, lb[u]);
    }
    __syncthreads();
    #pragma unroll
    for (int ks = 0; ks < 2; ks++){
      short8 af[4], bv[4];
      #pragma unroll
      for (int i = 0; i < 4; i++){
        af[i] = *(const short8*)&As[(wm*64 + i*16 + l15)*64 + ((ks*32 + kg*8) ^ sx)];
        bv[i] = *(const short8*)&Bs[(wn*64 + i*16 + l15)*64 + ((ks*32 + kg*8) ^ sx)];
      }
      #pragma unroll
      for (int i = 0; i < 4; i++)
        #pragma unroll
        for (int j = 0; j < 4; j++)
          acc[i][j] = mfma_bf16(af[i], bv[j], acc[i][j]);
    }
  }

  #pragma unroll
  for (int i = 0; i < 4; i++){
    const long mb = bm + wm*64 + i*16 + kg*4;
    #pragma unroll
    for (int j = 0; j < 4; j++){
      const long n = bn + wn*64 + j*16 + l15;
      #pragma unroll
      for (int r = 0; r < 4; r++)
        C[(size_t)(mb + r) * N + n] = acc[i][j][r];
    }
  }
}

// ---------------------------------------------------------------------------
extern "C" void kernel_launch(void* const* d_in, const int* in_sizes, int n_in,
                              void* d_out, int out_size, void* d_ws, size_t ws_size,
                              hipStream_t stream)
{
  const float* q   = (const float*)d_in[0];
  const float* k   = (const float*)d_in[1];
  const float* v   = (const float*)d_in[2];
  const float* wq  = (const float*)d_in[3];
  const float* wk  = (const float*)d_in[4];
  const float* wv  = (const float*)d_in[5];
  const float* wo  = (const float*)d_in[6];
  const float* wg  = (const float*)d_in[7];
  const float* wxw = (const float*)d_in[8];
  const float* wxb = (const float*)d_in[9];
  const float* gnw = (const float*)d_in[10];
  const float* gnb = (const float*)d_in[11];

  // ws layout (47.2 MB). d_out (f32, 64 MB) doubles as Kx f32 scratch.
  char* ws = (char*)d_ws;
  unsigned short* A0   = (unsigned short*)(ws);             // 32 MB: Vx bf16 -> Agate bf16
  unsigned short* wh   = (unsigned short*)(ws + 33554432);  // 2 MB: wk_h -> wq_h
  unsigned short* wl   = (unsigned short*)(ws + 35651584);  // 2 MB: wk_l -> wq_l
  unsigned short* wAbf = (unsigned short*)(ws + 37748736);  // 2 MB: wv -> wo
  unsigned short* wgbf = (unsigned short*)(ws + 39845888);  // 2 MB
  unsigned short* wxh  = (unsigned short*)(ws + 41943040);  // 512 KB
  unsigned short* wxl  = (unsigned short*)(ws + 42467328);  // 512 KB
  float*          P    = (float*)(ws + 42991616);           // 2 MB
  float*          zs   = (float*)(ws + 45088768);           // 1 MB
  float*          zc   = (float*)(ws + 46137344);           // 16 KB
  float*          Qx   = (float*)(ws + 46153728);           // 1 MB
  float*          Kx   = (float*)d_out;                     // 64 MB f32 scratch

  const int M = 16384, N = 1024, K = 1024;
  dim3 blk(256);

  // weight prep
  cvt_split<<<512, blk, 0, stream>>>(wk, wh, wl, 131072);
  cvt_split<<<128, blk, 0, stream>>>(wxw, wxh, wxl, 32768);
  cvt_kernel<<<512, blk, 0, stream>>>(wv, wAbf, 131072);
  cvt_kernel<<<512, blk, 0, stream>>>(wg, wgbf, 131072);
  hipMemsetAsync(P, 0, 2097152, stream);

  // K path: k @ wk^T -> Kx f32 (xpos fused in epilogue), then proj
  gemm_split<0><<<dim3(8,128), blk, 0, stream>>>(k, wh, wl, Kx, M, N, K);
  proj_split<<<dim3(16,4,8), blk, 0, stream>>>(Kx, wxh, wxl, P);

  // V path: v @ wv^T -> A0 bf16, proj
  gemm_af32<0><<<dim3(8,128), blk, 0, stream>>>(v, wAbf, A0, M, N, K, nullptr, nullptr);
  proj_bf16<<<dim3(16,4,8), blk, 0, stream>>>(A0, wxh, P);
  cvt_kernel<<<512, blk, 0, stream>>>(wo, wAbf, 131072);   // wv dead -> wo

  // Q path: gather 64 rows/batch, xpos fused, attention
  cvt_split<<<512, blk, 0, stream>>>(wq, wh, wl, 131072);  // wk dead -> wq
  gemm_split<1><<<dim3(8,2), blk, 0, stream>>>(q, wh, wl, Qx, 256, N, K);
  attn_kernel<<<64, 256, 0, stream>>>(P, Qx, wxb, gnw, gnb, zs, zc);

  // Gate path: G = silu((q @ wg^T) * z) fused in epilogue -> A0, final GEMM
  gemm_af32<1><<<dim3(8,128), blk, 0, stream>>>(q, wgbf, A0, M, N, K, zs, zc);
  gemm_bt<<<dim3(8,128), blk, 0, stream>>>(A0, wAbf, (float*)d_out, M, N, K);
}

// Round 4
// 593.554 us; speedup vs baseline: 1.1339x; 1.1339x over previous
//
#include <hip/hip_runtime.h>
#include <hip/hip_bf16.h>

#define DEVI __device__ __forceinline__

typedef __attribute__((ext_vector_type(8))) short  short8;
typedef __attribute__((ext_vector_type(4))) float  floatx4;
typedef __attribute__((ext_vector_type(8))) __bf16 bf16x8;

DEVI float b2f(unsigned short u){ union{unsigned int i; float f;} x; x.i=((unsigned int)u)<<16; return x.f; }
DEVI unsigned short f2b(float f){
  union{float ff; unsigned int i;} x; x.ff=f;
  unsigned int r = x.i + 0x7fffu + ((x.i>>16)&1u);
  return (unsigned short)(r>>16);
}

DEVI void lds_dma16(const void* g, void* l){
  __builtin_amdgcn_global_load_lds((const __attribute__((address_space(1))) void*)g,
                                   (__attribute__((address_space(3))) void*)l, 16, 0, 0);
}

DEVI floatx4 mfma_bf16(short8 a, short8 b, floatx4 c){
  return __builtin_amdgcn_mfma_f32_16x16x32_bf16(
      __builtin_bit_cast(bf16x8, a), __builtin_bit_cast(bf16x8, b), c, 0, 0, 0);
}

// XCD-chunked tile remap (T1). For dim3(8,128) grids flat%8 == blockIdx.x,
// so XCD x gets bm-rows [16x,16x+16) x all 8 bn -> co-resident working set
// ~8 A-panels + 8 B-panels (~L2-sized) instead of the full 64MB A per XCD.
// Identity for other grids (e.g. the 16-block Q gemm).
DEVI void tile_remap(long& bmi, long& bni){
  const int bx = blockIdx.x, by = blockIdx.y;
  if (gridDim.y == 128){
    bni = (long)(by & 7);
    bmi = (long)((bx << 4) + (by >> 3));
  } else {
    bni = bx; bmi = by;
  }
}

// LDS swizzle (both-sides XOR, rule 21): tile [128][64] bf16, 8-el chunks.
// LDS(row, c) holds global chunk c ^ (row&7). DMA dest stays linear
// (base + lane*16); SOURCE column inverse-permuted; reg-staged writes XOR
// the ds_write address. Fragment reads XOR with (l15&7)*8.
// Verified: SQ_LDS_BANK_CONFLICT == 0 (round-3 counters).

// ---------------------------------------------------------------------------
// f32 -> bf16 (single) elementwise
// ---------------------------------------------------------------------------
__global__ void cvt_kernel(const float* __restrict__ src, unsigned short* __restrict__ dst, int n8)
{
  const int i = blockIdx.x * 256 + threadIdx.x;
  if (i >= n8) return;
  floatx4 a = ((const floatx4*)src)[2*(size_t)i];
  floatx4 b = ((const floatx4*)src)[2*(size_t)i + 1];
  short8 o;
  o[0]=(short)f2b(a[0]); o[1]=(short)f2b(a[1]); o[2]=(short)f2b(a[2]); o[3]=(short)f2b(a[3]);
  o[4]=(short)f2b(b[0]); o[5]=(short)f2b(b[1]); o[6]=(short)f2b(b[2]); o[7]=(short)f2b(b[3]);
  *(short8*)&dst[(size_t)i*8] = o;
}

// ---------------------------------------------------------------------------
// f32 -> (hi, lo) bf16 split: hi = rne(x), lo = rne(x - hi).
// ---------------------------------------------------------------------------
__global__ void cvt_split(const float* __restrict__ src, unsigned short* __restrict__ dh,
                          unsigned short* __restrict__ dl, int n8)
{
  const int i = blockIdx.x * 256 + threadIdx.x;
  if (i >= n8) return;
  floatx4 a = ((const floatx4*)src)[2*(size_t)i];
  floatx4 b = ((const floatx4*)src)[2*(size_t)i + 1];
  short8 h, l;
  #pragma unroll
  for (int j = 0; j < 8; j++){
    float x = (j < 4) ? a[j] : b[j-4];
    unsigned short hb = f2b(x);
    h[j] = (short)hb;
    l[j] = (short)f2b(x - b2f(hb));
  }
  *(short8*)&dh[(size_t)i*8] = h;
  *(short8*)&dl[(size_t)i*8] = l;
}

// ---------------------------------------------------------------------------
// C(bf16) = A(f32) @ Bw(bf16)^T.  BK=64, swizzled LDS, T14 A-prefetch,
// XCD remap, 3 blocks/CU. GATE=1: fused z*silu epilogue.
// ---------------------------------------------------------------------------
template<int GATE>
__global__ __launch_bounds__(256, 3)
void gemm_af32(const float* __restrict__ A, const unsigned short* __restrict__ Bw,
               unsigned short* __restrict__ C, int M, int N, int K,
               const float* __restrict__ zs, const float* __restrict__ zc)
{
  __shared__ __align__(16) short As[128*64];
  __shared__ __align__(16) short Bs[128*64];
  const int t    = threadIdx.x;
  const int lane = t & 63;
  const int w    = t >> 6, wm = w >> 1, wn = w & 1;
  const int l15  = lane & 15, kg = lane >> 4;
  const int sx   = (l15 & 7) * 8;                    // read-side swizzle
  long bmi, bni; tile_remap(bmi, bni);
  const long bm = bmi * 128, bn = bni * 128;

  const int sr = t >> 3, sc8 = (t & 7) * 8;
  const int scx = sc8 ^ ((sr & 7) * 8);              // write/source-side swizzle
  const unsigned short* pb[4];
  const float* pa[4];
  short *lb[4], *la[4];
  #pragma unroll
  for (int u = 0; u < 4; u++){
    pb[u] = Bw + (bn + sr + u*32) * (size_t)K + scx; // inverse-swizzled source
    pa[u] = A  + (bm + sr + u*32) * (size_t)K + sc8; // plain source
    lb[u] = &Bs[(sr + u*32)*64 + sc8];               // linear DMA dest
    la[u] = &As[(sr + u*32)*64 + scx];               // swizzled ds_write dest
  }

  floatx4 acc[4][4] = {};
  floatx4 cur[8], nxt[8];
  #pragma unroll
  for (int u = 0; u < 4; u++){
    cur[2*u]   = *(const floatx4*)(pa[u]);
    cur[2*u+1] = *(const floatx4*)(pa[u] + 4);
  }

  for (int k0 = 0; k0 < K; k0 += 64){
    __syncthreads();
    #pragma unroll
    for (int u = 0; u < 4; u++) lds_dma16(pb[u] + k0, lb[u]);
    #pragma unroll
    for (int u = 0; u < 4; u++){
      short8 h;
      #pragma unroll
      for (int j = 0; j < 8; j++){
        float x = (j < 4) ? cur[2*u][j] : cur[2*u+1][j-4];
        h[j] = (short)f2b(x);
      }
      *(short8*)la[u] = h;
    }
    __syncthreads();
    // T14: next A-tile loads hide under the MFMAs, drain at next barrier.
    const int kn = (k0 + 64 < K) ? (k0 + 64) : k0;
    #pragma unroll
    for (int u = 0; u < 4; u++){
      nxt[2*u]   = *(const floatx4*)(pa[u] + kn);
      nxt[2*u+1] = *(const floatx4*)(pa[u] + kn + 4);
    }
    #pragma unroll
    for (int ks = 0; ks < 2; ks++){
      short8 af[4], bv[4];
      #pragma unroll
      for (int i = 0; i < 4; i++){
        af[i] = *(const short8*)&As[(wm*64 + i*16 + l15)*64 + ((ks*32 + kg*8) ^ sx)];
        bv[i] = *(const short8*)&Bs[(wn*64 + i*16 + l15)*64 + ((ks*32 + kg*8) ^ sx)];
      }
      #pragma unroll
      for (int i = 0; i < 4; i++)
        #pragma unroll
        for (int j = 0; j < 4; j++)
          acc[i][j] = mfma_bf16(af[i], bv[j], acc[i][j]);
    }
    #pragma unroll
    for (int r8 = 0; r8 < 8; r8++) cur[r8] = nxt[r8];
  }

  if (GATE){
    #pragma unroll
    for (int i = 0; i < 4; i++){
      const long mb = bm + wm*64 + i*16 + kg*4;
      #pragma unroll
      for (int r = 0; r < 4; r++){
        const long row = mb + r;
        const int  ss  = (int)(row & 4095);
        const long bb  = row >> 12;
        const float* zr = (ss < 64) ? (zs + (((size_t)(bb*64 + ss)) << 10))
                                    : (zc + ((size_t)bb << 10));
        #pragma unroll
        for (int j = 0; j < 4; j++){
          const long n = bn + wn*64 + j*16 + l15;
          float g = acc[i][j][r] * zr[n];
          float sig = 1.0f / (1.0f + __expf(-g));
          C[(size_t)row * N + n] = f2b(g * sig);
        }
      }
    }
  } else {
    #pragma unroll
    for (int i = 0; i < 4; i++){
      const long mb = bm + wm*64 + i*16 + kg*4;
      #pragma unroll
      for (int j = 0; j < 4; j++){
        const long n = bn + wn*64 + j*16 + l15;
        #pragma unroll
        for (int r = 0; r < 4; r++)
          C[(size_t)(mb + r) * N + n] = f2b(acc[i][j][r]);
      }
    }
  }
}

// ---------------------------------------------------------------------------
// C(f32) = xpos( A(f32) @ B^T ) with split-bf16 (3-term). BK=64, swizzled LDS,
// T14 A-prefetch, XCD remap. xpos fused in epilogue (partner col = lane^1).
// QG=1: A-row gather r -> (r>>6)*4096 + (r&63), position = row & 63.
// ---------------------------------------------------------------------------
template<int QG>
__global__ __launch_bounds__(256, 2)
void gemm_split(const float* __restrict__ A, const unsigned short* __restrict__ Bh,
                const unsigned short* __restrict__ Bl, float* __restrict__ C,
                int M, int N, int K)
{
  __shared__ __align__(16) short Ash[128*64];
  __shared__ __align__(16) short Asl[128*64];
  __shared__ __align__(16) short Bsh[128*64];
  __shared__ __align__(16) short Bsl[128*64];
  const int t    = threadIdx.x;
  const int lane = t & 63;
  const int w    = t >> 6, wm = w >> 1, wn = w & 1;
  const int l15  = lane & 15, kg = lane >> 4;
  const int sx   = (l15 & 7) * 8;
  long bmi, bni; tile_remap(bmi, bni);
  const long bm = bmi * 128, bn = bni * 128;

  const int sr = t >> 3, sc8 = (t & 7) * 8;
  const int scx = sc8 ^ ((sr & 7) * 8);
  const unsigned short *pbh[4], *pbl[4];
  const float* pa[4];
  short *lbh[4], *lbl[4], *lah[4], *lal[4];
  #pragma unroll
  for (int u = 0; u < 4; u++){
    pbh[u] = Bh + (bn + sr + u*32) * (size_t)K + scx;
    pbl[u] = Bl + (bn + sr + u*32) * (size_t)K + scx;
    long ar = bm + sr + u*32;
    if (QG) ar = (ar >> 6) * 4096 + (ar & 63);
    pa[u]  = A + ar * (size_t)K + sc8;
    lbh[u] = &Bsh[(sr + u*32)*64 + sc8];
    lbl[u] = &Bsl[(sr + u*32)*64 + sc8];
    lah[u] = &Ash[(sr + u*32)*64 + scx];
    lal[u] = &Asl[(sr + u*32)*64 + scx];
  }

  floatx4 acc[4][4] = {};
  floatx4 cur[8], nxt[8];
  #pragma unroll
  for (int u = 0; u < 4; u++){
    cur[2*u]   = *(const floatx4*)(pa[u]);
    cur[2*u+1] = *(const floatx4*)(pa[u] + 4);
  }

  for (int k0 = 0; k0 < K; k0 += 64){
    __syncthreads();
    #pragma unroll
    for (int u = 0; u < 4; u++){
      lds_dma16(pbh[u] + k0, lbh[u]);
      lds_dma16(pbl[u] + k0, lbl[u]);
    }
    #pragma unroll
    for (int u = 0; u < 4; u++){
      short8 h, l;
      #pragma unroll
      for (int j = 0; j < 8; j++){
        float x = (j < 4) ? cur[2*u][j] : cur[2*u+1][j-4];
        unsigned short hb = f2b(x);
        h[j] = (short)hb;
        l[j] = (short)f2b(x - b2f(hb));
      }
      *(short8*)lah[u] = h;
      *(short8*)lal[u] = l;
    }
    __syncthreads();
    // T14: next A-tile loads overlap the 96 MFMAs below.
    const int kn = (k0 + 64 < K) ? (k0 + 64) : k0;
    #pragma unroll
    for (int u = 0; u < 4; u++){
      nxt[2*u]   = *(const floatx4*)(pa[u] + kn);
      nxt[2*u+1] = *(const floatx4*)(pa[u] + kn + 4);
    }
    #pragma unroll
    for (int ks = 0; ks < 2; ks++){
      short8 afh[4], afl[4], bvh[4], bvl[4];
      #pragma unroll
      for (int i = 0; i < 4; i++){
        const int ro = (ks*32 + kg*8) ^ sx;
        afh[i] = *(const short8*)&Ash[(wm*64 + i*16 + l15)*64 + ro];
        afl[i] = *(const short8*)&Asl[(wm*64 + i*16 + l15)*64 + ro];
        bvh[i] = *(const short8*)&Bsh[(wn*64 + i*16 + l15)*64 + ro];
        bvl[i] = *(const short8*)&Bsl[(wn*64 + i*16 + l15)*64 + ro];
      }
      #pragma unroll
      for (int i = 0; i < 4; i++)
        #pragma unroll
        for (int j = 0; j < 4; j++){
          acc[i][j] = mfma_bf16(afh[i], bvh[j], acc[i][j]);
          acc[i][j] = mfma_bf16(afh[i], bvl[j], acc[i][j]);
          acc[i][j] = mfma_bf16(afl[i], bvh[j], acc[i][j]);
        }
    }
    #pragma unroll
    for (int r8 = 0; r8 < 8; r8++) cur[r8] = nxt[r8];
  }

  // fused xpos epilogue. col pairs (2ip, 2ip+1) sit in lanes (l, l^1).
  const int smask = QG ? 63 : 4095;
  #pragma unroll
  for (int j = 0; j < 4; j++){
    const long n  = bn + wn*64 + j*16 + l15;
    const int  ip = (int)(n >> 1);
    const float lsv  = __logf((2.0f*ip + 409.6f) * (1.0f/1433.6f));
    const float invf = __expf(-(float)ip * (9.2103403720f/512.0f));  // 10000^(-ip/512)
    const float sgn  = (n & 1) ? 1.0f : -1.0f;
    #pragma unroll
    for (int i = 0; i < 4; i++){
      const long mb = bm + wm*64 + i*16 + kg*4;
      #pragma unroll
      for (int r = 0; r < 4; r++){
        float x = acc[i][j][r];
        float p = __shfl_xor(x, 1);
        const float fs = (float)((int)((mb + r) & smask));
        const float scale = __expf(lsv * fs * (1.0f/512.0f));
        float sn, cs;
        __sincosf(fs * invf, &sn, &cs);
        sn *= scale; cs *= scale;
        C[(size_t)(mb + r) * N + n] = x*cs + sgn*(p*sn);
      }
    }
  }
}

// ---------------------------------------------------------------------------
// Split-precision projection: P[b*2][e][d'] += sum_s wxw[e,s]*X[b][s,d'].
// ---------------------------------------------------------------------------
__global__ __launch_bounds__(256, 2)
void proj_split(const float* __restrict__ X0, const unsigned short* __restrict__ wxh,
                const unsigned short* __restrict__ wxl, float* __restrict__ P)
{
  __shared__ __align__(16) short Wsh[64*32];
  __shared__ __align__(16) short Wsl[64*32];
  __shared__ __align__(16) short Xth[64*40];
  __shared__ __align__(16) short Xtl[64*40];
  const int t = threadIdx.x, w = t >> 6, lane = t & 63;
  const int l15 = lane & 15, kg = lane >> 4;
  const int d0 = blockIdx.x * 64;
  const int b  = blockIdx.y;
  const float* X = X0 + (size_t)b * 4096 * 1024;
  const int s0 = blockIdx.z * 512;
  const int ssr = t >> 3, ddr = (t & 7) * 8;
  floatx4 acc[4] = {};

  for (int kk = 0; kk < 512; kk += 32){
    const int s = s0 + kk;
    floatx4 x0 = *(const floatx4*)&X[(size_t)(s + ssr) * 1024 + d0 + ddr];
    floatx4 x1 = *(const floatx4*)&X[(size_t)(s + ssr) * 1024 + d0 + ddr + 4];
    __syncthreads();
    lds_dma16(&wxh[(size_t)(t >> 2) * 4096 + s + (t & 3) * 8], &Wsh[t*8]);
    lds_dma16(&wxl[(size_t)(t >> 2) * 4096 + s + (t & 3) * 8], &Wsl[t*8]);
    float xv[8] = {x0[0],x0[1],x0[2],x0[3],x1[0],x1[1],x1[2],x1[3]};
    #pragma unroll
    for (int j = 0; j < 8; j++){
      unsigned short hb = f2b(xv[j]);
      Xth[(ddr + j) * 40 + ssr] = (short)hb;
      Xtl[(ddr + j) * 40 + ssr] = (short)f2b(xv[j] - b2f(hb));
    }
    __syncthreads();
    short8 afh = *(const short8*)&Wsh[(w*16 + l15)*32 + kg*8];
    short8 afl = *(const short8*)&Wsl[(w*16 + l15)*32 + kg*8];
    #pragma unroll
    for (int j = 0; j < 4; j++){
      short8 bvh = *(const short8*)&Xth[(j*16 + l15)*40 + kg*8];
      short8 bvl = *(const short8*)&Xtl[(j*16 + l15)*40 + kg*8];
      acc[j] = mfma_bf16(afh, bvh, acc[j]);
      acc[j] = mfma_bf16(afh, bvl, acc[j]);
      acc[j] = mfma_bf16(afl, bvh, acc[j]);
    }
  }
  float* Pb = P + (size_t)(b*2) * 65536;
  #pragma unroll
  for (int j = 0; j < 4; j++)
    #pragma unroll
    for (int r = 0; r < 4; r++)
      atomicAdd(&Pb[(w*16 + kg*4 + r) * 1024 + d0 + j*16 + l15], acc[j][r]);
}

// ---------------------------------------------------------------------------
// bf16 projection for V: P[b*2+1][e][d'] += sum_s wxw_h[e,s]*X[b][s,d']
// ---------------------------------------------------------------------------
__global__ __launch_bounds__(256, 2)
void proj_bf16(const unsigned short* __restrict__ X0, const unsigned short* __restrict__ wxw_bf,
               float* __restrict__ P)
{
  __shared__ __align__(16) short Ws[64*32];
  __shared__ __align__(16) short Xt[64*40];
  const int t = threadIdx.x, w = t >> 6, lane = t & 63;
  const int l15 = lane & 15, kg = lane >> 4;
  const int d0 = blockIdx.x * 64;
  const int b  = blockIdx.y;
  const unsigned short* X = X0 + (size_t)b * 4096 * 1024;
  const int s0 = blockIdx.z * 512;
  const int ssr = t >> 3, ddr = (t & 7) * 8;
  floatx4 acc[4] = {};

  for (int kk = 0; kk < 512; kk += 32){
    const int s = s0 + kk;
    short8 xv = *(const short8*)&X[(size_t)(s + ssr) * 1024 + d0 + ddr];
    __syncthreads();
    lds_dma16(&wxw_bf[(size_t)(t >> 2) * 4096 + s + (t & 3) * 8], &Ws[t*8]);
    #pragma unroll
    for (int j = 0; j < 8; j++) Xt[(ddr + j) * 40 + ssr] = xv[j];
    __syncthreads();
    short8 af = *(const short8*)&Ws[(w*16 + l15)*32 + kg*8];
    #pragma unroll
    for (int j = 0; j < 4; j++){
      short8 bv = *(const short8*)&Xt[(j*16 + l15)*40 + kg*8];
      acc[j] = mfma_bf16(af, bv, acc[j]);
    }
  }
  float* Pb = P + (size_t)(b*2 + 1) * 65536;
  #pragma unroll
  for (int j = 0; j < 4; j++)
    #pragma unroll
    for (int r = 0; r < 4; r++)
      atomicAdd(&Pb[(w*16 + kg*4 + r) * 1024 + d0 + j*16 + l15], acc[j][r]);
}

// ---------------------------------------------------------------------------
// Per (b,h) attention + group norm. 256 threads: wave w owns e-quarter for
// scores and g-quarter for outputs; scores round-trip through LDS.
// Masked score entries are literal ZEROS (matches reference softmax).
// ---------------------------------------------------------------------------
__global__ __launch_bounds__(256)
void attn_kernel(const float* __restrict__ P, const float* __restrict__ Qx,
                 const float* __restrict__ wxb,
                 const float* __restrict__ gnw, const float* __restrict__ gnb,
                 float* __restrict__ zs, float* __restrict__ zc)
{
  __shared__ __align__(16) float kps[64*64];   // [e][d]
  __shared__ __align__(16) float vps[64*64];   // [e][f]
  __shared__ __align__(16) float scs[64*65];   // [e][s], stride 65
  __shared__ float pm[256];
  __shared__ float ym[64];
  const int t = threadIdx.x;
  const int w = t >> 6, s = t & 63;
  const int b = blockIdx.x >> 4, h = blockIdx.x & 15;
  const float* Pk = P + (size_t)(2*b) * 65536 + h*64;
  const float* Pv = Pk + 65536;

  {
    const int e = t >> 2, c = (t & 3) * 16;
    const float wb = wxb[e];
    #pragma unroll
    for (int j = 0; j < 4; j++){
      floatx4 kv = *(const floatx4*)&Pk[(size_t)e*1024 + c + 4*j];
      floatx4 vv = *(const floatx4*)&Pv[(size_t)e*1024 + c + 4*j];
      kv.x += wb; kv.y += wb; kv.z += wb; kv.w += wb;
      vv.x += wb; vv.y += wb; vv.z += wb; vv.w += wb;
      *(floatx4*)&kps[e*64 + c + 4*j] = kv;
      *(floatx4*)&vps[e*64 + c + 4*j] = vv;
    }
  }
  __syncthreads();

  float qf[64];
  const floatx4* q4 = (const floatx4*)(Qx + (size_t)(b*64 + s)*1024 + h*64);
  #pragma unroll
  for (int i = 0; i < 16; i++){
    floatx4 qq = q4[i];
    qf[4*i] = qq.x; qf[4*i+1] = qq.y; qf[4*i+2] = qq.z; qf[4*i+3] = qq.w;
  }

  // scores for this wave's e-quarter -> LDS [e][s]
  #pragma unroll
  for (int eo = 0; eo < 16; eo++){
    const int e = w*16 + eo;
    const floatx4* kp4 = (const floatx4*)&kps[e*64];
    float dot = 0.f;
    #pragma unroll
    for (int d = 0; d < 16; d++){
      floatx4 kv = kp4[d];
      dot += qf[4*d]*kv.x + qf[4*d+1]*kv.y + qf[4*d+2]*kv.z + qf[4*d+3]*kv.w;
    }
    scs[e*65 + s] = dot;
  }
  // partial column-sum of vps for the zc tail
  {
    float am = 0.f;
    #pragma unroll
    for (int eo = 0; eo < 16; eo++) am += vps[(w*16 + eo)*64 + s];
    pm[t] = am;
  }
  __syncthreads();

  const float lg = -3.4657359028f - 0.1848392483f * (float)h;
  const float gamma = 1.0f - __expf(lg);
  float sc[64];
  #pragma unroll
  for (int e = 0; e < 64; e++) sc[e] = scs[e*65 + s];
  float dec = 1.0f;
  #pragma unroll
  for (int e = 0; e < 64; e++){
    bool on = (e >= s);
    sc[e] = on ? sc[e]*dec : 0.0f;
    if (on) dec *= gamma;
  }
  float mx = -1e30f;
  #pragma unroll
  for (int e = 0; e < 64; e++) mx = fmaxf(mx, sc[e]);
  float Z = 0.f;
  #pragma unroll
  for (int e = 0; e < 64; e++){ sc[e] = __expf(sc[e] - mx); Z += sc[e]; }
  const float rz = 1.0f / Z;

  #pragma unroll
  for (int go = 0; go < 4; go++){
    const int g = w*4 + go;
    floatx4 y = {0.f,0.f,0.f,0.f};
    #pragma unroll
    for (int e = 0; e < 64; e++){
      floatx4 vv = *(const floatx4*)&vps[e*64 + g*4];
      y += sc[e] * vv;
    }
    y *= rz;
    float mu = (y.x + y.y + y.z + y.w) * 0.25f;
    float a0 = y.x-mu, a1 = y.y-mu, a2 = y.z-mu, a3 = y.w-mu;
    float inv = rsqrtf((a0*a0 + a1*a1 + a2*a2 + a3*a3)*0.25f + 1e-5f);
    floatx4 o;
    o.x = a0*inv*gnw[g*4+0] + gnb[g*4+0];
    o.y = a1*inv*gnw[g*4+1] + gnb[g*4+1];
    o.z = a2*inv*gnw[g*4+2] + gnb[g*4+2];
    o.w = a3*inv*gnw[g*4+3] + gnb[g*4+3];
    *(floatx4*)&zs[(size_t)(b*64 + s)*1024 + h*64 + g*4] = o;
  }

  if (w == 0)
    ym[s] = (pm[s] + pm[64+s] + pm[128+s] + pm[192+s]) * (1.0f/64.0f);
  __syncthreads();
  if (t < 16){
    float a0 = ym[t*4], a1 = ym[t*4+1], a2 = ym[t*4+2], a3 = ym[t*4+3];
    float mu = (a0+a1+a2+a3)*0.25f;
    a0 -= mu; a1 -= mu; a2 -= mu; a3 -= mu;
    float inv = rsqrtf((a0*a0+a1*a1+a2*a2+a3*a3)*0.25f + 1e-5f);
    zc[(size_t)b*1024 + h*64 + t*4+0] = a0*inv*gnw[t*4+0] + gnb[t*4+0];
    zc[(size_t)b*1024 + h*64 + t*4+1] = a1*inv*gnw[t*4+1] + gnb[t*4+1];
    zc[(size_t)b*1024 + h*64 + t*4+2] = a2*inv*gnw[t*4+2] + gnb[t*4+2];
    zc[(size_t)b*1024 + h*64 + t*4+3] = a3*inv*gnw[t*4+3] + gnb[t*4+3];
  }
}

// ---------------------------------------------------------------------------
// C(f32) = A(bf16) @ B(bf16)^T — final GEMM, BK=64, swizzled LDS, both DMA,
// XCD remap, 3 blocks/CU.
// ---------------------------------------------------------------------------
__global__ __launch_bounds__(256, 3)
void gemm_bt(const unsigned short* __restrict__ A, const unsigned short* __restrict__ Bw,
             float* __restrict__ C, int M, int N, int K)
{
  __shared__ __align__(16) short As[128*64];
  __shared__ __align__(16) short Bs[128*64];
  const int t    = threadIdx.x;
  const int lane = t & 63;
  const int w    = t >> 6, wm = w >> 1, wn = w & 1;
  const int l15  = lane & 15, kg = lane >> 4;
  const int sx   = (l15 & 7) * 8;
  long bmi, bni; tile_remap(bmi, bni);
  const long bm = bmi * 128, bn = bni * 128;

  const int sr = t >> 3, sc8 = (t & 7) * 8;
  const int scx = sc8 ^ ((sr & 7) * 8);
  const unsigned short *pa[4], *pb[4];
  short *la[4], *lb[4];
  #pragma unroll
  for (int u = 0; u < 4; u++){
    pa[u] = A  + (bm + sr + u*32) * (size_t)K + scx;
    pb[u] = Bw + (bn + sr + u*32) * (size_t)K + scx;
    la[u] = &As[(sr + u*32)*64 + sc8];
    lb[u] = &Bs[(sr + u*32)*64 + sc8];
  }

  floatx4 acc[4][4] = {};

  for (int k0 = 0; k0 < K; k0 += 64){
    __syncthreads();
    #pragma unroll
    for (int u = 0; u < 4; u++){
      lds_dma16(pa[u] + k0, la[u]);
      lds_dma16(pb[u] + k0, lb[u]);
    }
    __syncthreads();
    #pragma unroll
    for (int ks = 0; ks < 2; ks++){
      short8 af[4], bv[4];
      #pragma unroll
      for (int i = 0; i < 4; i++){
        af[i] = *(const short8*)&As[(wm*64 + i*16 + l15)*64 + ((ks*32 + kg*8) ^ sx)];
        bv[i] = *(const short8*)&Bs[(wn*64 + i*16 + l15)*64 + ((ks*32 + kg*8) ^ sx)];
      }
      #pragma unroll
      for (int i = 0; i < 4; i++)
        #pragma unroll
        for (int j = 0; j < 4; j++)
          acc[i][j] = mfma_bf16(af[i], bv[j], acc[i][j]);
    }
  }

  #pragma unroll
  for (int i = 0; i < 4; i++){
    const long mb = bm + wm*64 + i*16 + kg*4;
    #pragma unroll
    for (int j = 0; j < 4; j++){
      const long n = bn + wn*64 + j*16 + l15;
      #pragma unroll
      for (int r = 0; r < 4; r++)
        C[(size_t)(mb + r) * N + n] = acc[i][j][r];
    }
  }
}

// ---------------------------------------------------------------------------
extern "C" void kernel_launch(void* const* d_in, const int* in_sizes, int n_in,
                              void* d_out, int out_size, void* d_ws, size_t ws_size,
                              hipStream_t stream)
{
  const float* q   = (const float*)d_in[0];
  const float* k   = (const float*)d_in[1];
  const float* v   = (const float*)d_in[2];
  const float* wq  = (const float*)d_in[3];
  const float* wk  = (const float*)d_in[4];
  const float* wv  = (const float*)d_in[5];
  const float* wo  = (const float*)d_in[6];
  const float* wg  = (const float*)d_in[7];
  const float* wxw = (const float*)d_in[8];
  const float* wxb = (const float*)d_in[9];
  const float* gnw = (const float*)d_in[10];
  const float* gnb = (const float*)d_in[11];

  // ws layout (47.2 MB). d_out (f32, 64 MB) doubles as Kx f32 scratch.
  char* ws = (char*)d_ws;
  unsigned short* A0   = (unsigned short*)(ws);             // 32 MB: Vx bf16 -> Agate bf16
  unsigned short* wh   = (unsigned short*)(ws + 33554432);  // 2 MB: wk_h -> wq_h
  unsigned short* wl   = (unsigned short*)(ws + 35651584);  // 2 MB: wk_l -> wq_l
  unsigned short* wAbf = (unsigned short*)(ws + 37748736);  // 2 MB: wv -> wo
  unsigned short* wgbf = (unsigned short*)(ws + 39845888);  // 2 MB
  unsigned short* wxh  = (unsigned short*)(ws + 41943040);  // 512 KB
  unsigned short* wxl  = (unsigned short*)(ws + 42467328);  // 512 KB
  float*          P    = (float*)(ws + 42991616);           // 2 MB
  float*          zs   = (float*)(ws + 45088768);           // 1 MB
  float*          zc   = (float*)(ws + 46137344);           // 16 KB
  float*          Qx   = (float*)(ws + 46153728);           // 1 MB
  float*          Kx   = (float*)d_out;                     // 64 MB f32 scratch

  const int M = 16384, N = 1024, K = 1024;
  dim3 blk(256);

  // weight prep
  cvt_split<<<512, blk, 0, stream>>>(wk, wh, wl, 131072);
  cvt_split<<<128, blk, 0, stream>>>(wxw, wxh, wxl, 32768);
  cvt_kernel<<<512, blk, 0, stream>>>(wv, wAbf, 131072);
  cvt_kernel<<<512, blk, 0, stream>>>(wg, wgbf, 131072);
  hipMemsetAsync(P, 0, 2097152, stream);

  // K path: k @ wk^T -> Kx f32 (xpos fused in epilogue), then proj
  gemm_split<0><<<dim3(8,128), blk, 0, stream>>>(k, wh, wl, Kx, M, N, K);
  proj_split<<<dim3(16,4,8), blk, 0, stream>>>(Kx, wxh, wxl, P);

  // V path: v @ wv^T -> A0 bf16, proj
  gemm_af32<0><<<dim3(8,128), blk, 0, stream>>>(v, wAbf, A0, M, N, K, nullptr, nullptr);
  proj_bf16<<<dim3(16,4,8), blk, 0, stream>>>(A0, wxh, P);
  cvt_kernel<<<512, blk, 0, stream>>>(wo, wAbf, 131072);   // wv dead -> wo

  // Q path: gather 64 rows/batch, xpos fused, attention
  cvt_split<<<512, blk, 0, stream>>>(wq, wh, wl, 131072);  // wk dead -> wq
  gemm_split<1><<<dim3(8,2), blk, 0, stream>>>(q, wh, wl, Qx, 256, N, K);
  attn_kernel<<<64, 256, 0, stream>>>(P, Qx, wxb, gnw, gnb, zs, zc);

  // Gate path: G = silu((q @ wg^T) * z) fused in epilogue -> A0, final GEMM
  gemm_af32<1><<<dim3(8,128), blk, 0, stream>>>(q, wgbf, A0, M, N, K, zs, zc);
  gemm_bt<<<dim3(8,128), blk, 0, stream>>>(A0, wAbf, (float*)d_out, M, N, K);
}